// Round 3
// baseline (229.759 us; speedup 1.0000x reference)
//
#include <hip/hip_runtime.h>
#include <hip/hip_fp16.h>

#define N_DET 128
#define N_T   2048
#define NPIX  65536   // 256*256
#define NBATCH 4
#define PT 256        // pixels per block (grid = 256 blocks = 1/CU)

typedef float f4_t __attribute__((ext_vector_type(4)));

// Kernel 1: transpose+pack sino (B, N_DET, N_T) fp32 -> ws (N_DET, N_T) of
// 8-byte records { s_t[b0..b3] } as 4 fp16. ws = 2 MB (L2-resident per XCD).
__global__ __launch_bounds__(256) void sino_pack_kernel(
    const float* __restrict__ sino, float2* __restrict__ ws) {
  const int idx = blockIdx.x * blockDim.x + threadIdx.x;  // idx = d*N_T + t
  const __half2 lo = __floats2half2_rn(
      __builtin_nontemporal_load(sino + 0 * N_DET * N_T + idx),
      __builtin_nontemporal_load(sino + 1 * N_DET * N_T + idx));
  const __half2 hi = __floats2half2_rn(
      __builtin_nontemporal_load(sino + 2 * N_DET * N_T + idx),
      __builtin_nontemporal_load(sino + 3 * N_DET * N_T + idx));
  union { struct { __half2 a, b; } h; float2 f; } u;
  u.h.a = lo;
  u.h.b = hi;
  ws[idx] = u.f;
}

// Kernel 2: block = 256 pixels x ALL 128 dets (NO atomics, out written once).
// 1024 threads: thread (pix = tid>>2, sub = tid&3) owns det quarter
// [sub*32, sub*32+32). 32 det-iters; iter `it` uses det sub*32+it, whose 4
// rows (one per quarter) are staged in double-buffered 2x64 KB LDS via
// global_load_lds width=16 (async, no VGPR round-trip; issue-at-top-of-iter
// overlaps the compute, the iter-end __syncthreads drain is exactly when the
// data is needed). lut: 256 B contiguous per thread, 16 b128 issued one iter
// ahead. Cross-sub reduction = 2 __shfl_xor (in-quad, free).
// Round-2 lesson: det-split across blocks cost 45 MB of atomic RMW HBM
// write amplification (WRITE_SIZE 16->61 MB); this removes it entirely.
__global__ __launch_bounds__(1024, 4) void das_lds_kernel(
    const float* __restrict__ lut, const float2* __restrict__ ws,
    float* __restrict__ out) {
  __shared__ __align__(16) float2 sbuf[2][4][N_T];  // 2 bufs x 4 rows = 128 KB
  __shared__ float apod_s[N_DET];                   // 512 B

  const int tid = threadIdx.x;
  const int pix = tid >> 2, sub = tid & 3;
  const int p = blockIdx.x * PT + pix;

  // Apodization table (one cosf per det per block, not per det per pixel).
  if (tid < N_DET)
    apod_s[tid] =
        0.5f - 0.5f * cosf(6.28318530717958647692f * ((float)tid / 127.0f));

  // This thread's lut line: 32 dets x 8 B = 256 B contiguous.
  const f4_t* lp =
      reinterpret_cast<const f4_t*>(lut + ((size_t)p * N_DET + sub * 32) * 2);
  f4_t l[16];
  l[0] = lp[0];

  // Staging geometry: wave w covers quarter q = w>>2, sub-slice sw = w&3.
  // Row (q*32+it) of ws (16 KB) -> sbuf[b][q]; per wave 4 KB as 4 x
  // (64 lanes x 16 B) linear spans — satisfies global_load_lds's
  // wave-uniform-base + lane*16 destination rule.
  const int w = tid >> 6, lane = tid & 63;
  const int q = w >> 2, sw = w & 3;
  const char* gbase = reinterpret_cast<const char*>(ws) + ((size_t)q << 19) +
                      (sw << 10) + lane * 16;
  char* lbase = reinterpret_cast<char*>(&sbuf[0][0][0]) + (q << 14) +
                (sw << 10) + lane * 16;

  auto stage = [&](int it, int b) {
#pragma unroll
    for (int rr = 0; rr < 4; ++rr) {
      __builtin_amdgcn_global_load_lds(
          (const __attribute__((address_space(1))) void*)(gbase +
                                                          ((size_t)it << 14) +
                                                          (rr << 12)),
          (__attribute__((address_space(3))) void*)(lbase + (b << 16) +
                                                    (rr << 12)),
          16, 0, 0);
    }
  };

  stage(0, 0);
  __syncthreads();  // drains stage(0) + l[0] + apod table

  float a0 = 0.f, a1 = 0.f, a2 = 0.f, a3 = 0.f;

#pragma unroll
  for (int it = 0; it < 32; ++it) {
    // Issue next iter's stage first: async loads run under this iter's compute.
    if (it + 1 < 32) stage(it + 1, (it + 1) & 1);
    // lut prefetch one iter ahead: l[j] first needed at iter 2j.
    if ((it & 1) == 1 && (it + 1) < 32) l[(it + 1) >> 1] = lp[(it + 1) >> 1];

    const float tof = (it & 1) ? l[it >> 1].z : l[it >> 1].x;
    const float al  = (it & 1) ? l[it >> 1].w : l[it >> 1].y;
    const float kf = floorf(tof);
    const bool valid = (kf >= 0.0f) && (kf < (float)(N_T - 1));
    const int k0 = (int)fminf(fmaxf(kf, 0.0f), (float)(N_T - 2));
    const float wgt = valid ? apod_s[sub * 32 + it] : 0.0f;

    const float2* sb = &sbuf[it & 1][sub][0];
    const float2 r0 = sb[k0];      // ds_read_b64: tap t
    const float2 r1 = sb[k0 + 1];  // ds_read_b64: tap t+1
    const __half2* h0 = reinterpret_cast<const __half2*>(&r0);
    const __half2* h1 = reinterpret_cast<const __half2*>(&r1);
    const float2 s0a = __half22float2(h0[0]);  // t:   b0,b1
    const float2 s0b = __half22float2(h0[1]);  // t:   b2,b3
    const float2 s1a = __half22float2(h1[0]);  // t+1: b0,b1
    const float2 s1b = __half22float2(h1[1]);  // t+1: b2,b3

    a0 += wgt * (s0a.x + al * (s1a.x - s0a.x));
    a1 += wgt * (s0a.y + al * (s1a.y - s0a.y));
    a2 += wgt * (s0b.x + al * (s1b.x - s0b.x));
    a3 += wgt * (s0b.y + al * (s1b.y - s0b.y));

    __syncthreads();  // buf(it^1) staged & everyone done reading buf(it&1)
  }

  // Combine the 4 det-quarters: subs are lanes {0..3} within each quad.
  a0 += __shfl_xor(a0, 1); a0 += __shfl_xor(a0, 2);
  a1 += __shfl_xor(a1, 1); a1 += __shfl_xor(a1, 2);
  a2 += __shfl_xor(a2, 1); a2 += __shfl_xor(a2, 2);
  a3 += __shfl_xor(a3, 1); a3 += __shfl_xor(a3, 2);

  if (sub == 0) {
    const float nrm = 1.0f / 63.5f;  // sum(apod) == 63.5 analytically
    out[0 * NPIX + p] = a0 * nrm;
    out[1 * NPIX + p] = a1 * nrm;
    out[2 * NPIX + p] = a2 * nrm;
    out[3 * NPIX + p] = a3 * nrm;
  }
}

// Fallback (no workspace): direct fp32 gather from original layout.
__global__ __launch_bounds__(256) void das_fallback_kernel(
    const float* __restrict__ lut, const float* __restrict__ S,
    float* __restrict__ out) {
  const int lane = threadIdx.x & 63;
  const int p = blockIdx.x * 4 + (threadIdx.x >> 6);

  const float4 lv =
      reinterpret_cast<const float4*>(lut + (size_t)p * 2 * N_DET)[lane];

  float acc0 = 0.f, acc1 = 0.f, acc2 = 0.f, acc3 = 0.f;
  float wsum = 0.f;

#pragma unroll
  for (int j = 0; j < 2; ++j) {
    const int d = 2 * lane + j;
    const float tof = j ? lv.z : lv.x;
    const float a   = j ? lv.w : lv.y;
    const float kf = floorf(tof);
    const bool valid = (kf >= 0.0f) && (kf < (float)(N_T - 1));
    const float kcl = fminf(fmaxf(kf, 0.0f), (float)(N_T - 2));
    const int k0 = (int)kcl;
    const float apd =
        0.5f - 0.5f * cosf(6.28318530717958647692f *
                           (1.0f / (float)(N_DET - 1)) * (float)d);
    wsum += apd;
    const float w = valid ? apd : 0.0f;
    const float om = 1.0f - a;
    const float* row = S + (size_t)d * N_T + k0;
    acc0 += w * (om * row[0 * N_DET * N_T] + a * row[0 * N_DET * N_T + 1]);
    acc1 += w * (om * row[1 * N_DET * N_T] + a * row[1 * N_DET * N_T + 1]);
    acc2 += w * (om * row[2 * N_DET * N_T] + a * row[2 * N_DET * N_T + 1]);
    acc3 += w * (om * row[3 * N_DET * N_T] + a * row[3 * N_DET * N_T + 1]);
  }

#pragma unroll
  for (int off = 32; off > 0; off >>= 1) {
    acc0 += __shfl_xor(acc0, off);
    acc1 += __shfl_xor(acc1, off);
    acc2 += __shfl_xor(acc2, off);
    acc3 += __shfl_xor(acc3, off);
    wsum += __shfl_xor(wsum, off);
  }

  if (lane == 0) {
    const float inv = 1.0f / fmaxf(wsum, 1.17549435e-38f);
    out[0 * NPIX + p] = acc0 * inv;
    out[1 * NPIX + p] = acc1 * inv;
    out[2 * NPIX + p] = acc2 * inv;
    out[3 * NPIX + p] = acc3 * inv;
  }
}

extern "C" void kernel_launch(void* const* d_in, const int* in_sizes, int n_in,
                              void* d_out, int out_size, void* d_ws, size_t ws_size,
                              hipStream_t stream) {
  const float* sino = (const float*)d_in[0];  // (B,1,N_DET,N_T) fp32
  const float* lut  = (const float*)d_in[1];  // (NY,NX,N_DET,2) fp32
  float* out = (float*)d_out;                 // (B,1,NY,NX) fp32

  const size_t need = (size_t)N_DET * N_T * 8;  // 2 MB packed ws
  if (ws_size >= need) {
    float2* ws = (float2*)d_ws;
    sino_pack_kernel<<<(N_DET * N_T) / 256, 256, 0, stream>>>(sino, ws);
    das_lds_kernel<<<NPIX / PT, 1024, 0, stream>>>(lut, ws, out);
  } else {
    das_fallback_kernel<<<NPIX / 4, 256, 0, stream>>>(lut, sino, out);
  }
}

// Round 4
// 126.022 us; speedup vs baseline: 1.8232x; 1.8232x over previous
//
#include <hip/hip_runtime.h>
#include <hip/hip_fp16.h>

#define N_DET 128
#define N_T   2048
#define NPIX  65536   // 256*256
#define NBATCH 4
#define SUBS 16               // det-slices per pixel (one thread each)
#define DPS (N_DET / SUBS)    // 8 dets per thread

typedef float f4_t __attribute__((ext_vector_type(4)));
// 16-byte vector with honest 8-byte alignment: gather of taps (t,t+1) x 4
// batches is an 8B-aligned global_load_dwordx4 (HW needs only dword align).
typedef float f4u_t __attribute__((ext_vector_type(4), aligned(8)));

// Kernel 1: transpose+pack sino (B, N_DET, N_T) fp32 -> ws (N_DET, N_T) of
// 8-byte records { s_t[b0..b3] } as 4 fp16. ws = 2 MB -> L2-resident per XCD.
__global__ __launch_bounds__(256) void sino_pack_kernel(
    const float* __restrict__ sino, float2* __restrict__ ws) {
  const int idx = blockIdx.x * blockDim.x + threadIdx.x;  // idx = d*N_T + t
  const __half2 lo = __floats2half2_rn(
      __builtin_nontemporal_load(sino + 0 * N_DET * N_T + idx),
      __builtin_nontemporal_load(sino + 1 * N_DET * N_T + idx));
  const __half2 hi = __floats2half2_rn(
      __builtin_nontemporal_load(sino + 2 * N_DET * N_T + idx),
      __builtin_nontemporal_load(sino + 3 * N_DET * N_T + idx));
  union { struct { __half2 a, b; } h; float2 f; } u;
  u.h.a = lo;
  u.h.b = hi;
  ws[idx] = u.f;
}

// Kernel 2: direct-gather, no LDS staging, no barriers, no atomics.
// Thread (p, sub) owns dets [sub*8, sub*8+8). Per det: one 16 B gather from
// the L2-resident ws covers both interp taps for all 4 batches. Reduction
// over the 16 subs = 4 in-wave shfl_xor levels; out written exactly once.
// Lessons encoded: r0-r2 showed the LDS family is latency/occupancy-bound
// (1 block/CU, barrier drains) and det-split-across-blocks pays atomic RMW
// amplification; r3 showed big per-thread arrays spill. Here: 8 waves/SIMD
// target (launch_bounds(256,8), ~64 VGPR), 8 independent gather chains per
// thread, only 512 B LDS (apod table).
__global__ __launch_bounds__(256, 8) void das_gather_kernel(
    const float* __restrict__ lut, const char* __restrict__ wsb,
    float* __restrict__ out) {
  __shared__ float apod_s[N_DET];  // 512 B

  const int tid = threadIdx.x;
  if (tid < N_DET)
    apod_s[tid] =
        0.5f - 0.5f * cosf(6.28318530717958647692f * ((float)tid / 127.0f));

  const int sub = tid & (SUBS - 1);
  const int p = (blockIdx.x * 256 + tid) >> 4;

  // This thread's lut line: 8 dets x 8 B = 64 B contiguous (wave: 4 KB).
  const f4_t* lp =
      reinterpret_cast<const f4_t*>(lut + ((size_t)p * N_DET + sub * DPS) * 2);
  f4_t l[DPS / 2];
#pragma unroll
  for (int i = 0; i < DPS / 2; ++i) l[i] = lp[i];

  __syncthreads();  // apod table ready

  float a0 = 0.f, a1 = 0.f, a2 = 0.f, a3 = 0.f;
  const unsigned rowbase = (unsigned)(sub * DPS) * (N_T * 8u);

#pragma unroll
  for (int j = 0; j < DPS; ++j) {
    const float tof = (j & 1) ? l[j >> 1].z : l[j >> 1].x;
    const float al  = (j & 1) ? l[j >> 1].w : l[j >> 1].y;
    const float kf = floorf(tof);
    const bool valid = (kf >= 0.0f) && (kf < (float)(N_T - 1));
    const int k0 = (int)fminf(fmaxf(kf, 0.0f), (float)(N_T - 2));
    const float w = valid ? apod_s[sub * DPS + j] : 0.0f;

    // 16 B gather: bytes [(d*N_T + k0)*8, +16) = records for taps t, t+1.
    const f4u_t g = *reinterpret_cast<const f4u_t*>(
        wsb + rowbase + (unsigned)(j * N_T * 8) + ((unsigned)k0 << 3));
    const __half2* h = reinterpret_cast<const __half2*>(&g);
    const float2 s0a = __half22float2(h[0]);  // t:   b0,b1
    const float2 s0b = __half22float2(h[1]);  // t:   b2,b3
    const float2 s1a = __half22float2(h[2]);  // t+1: b0,b1
    const float2 s1b = __half22float2(h[3]);  // t+1: b2,b3

    a0 += w * (s0a.x + al * (s1a.x - s0a.x));
    a1 += w * (s0a.y + al * (s1a.y - s0a.y));
    a2 += w * (s0b.x + al * (s1b.x - s0b.x));
    a3 += w * (s0b.y + al * (s1b.y - s0b.y));
  }

  // Combine the 16 det-slices (lanes 0..15 of each 16-lane group).
#pragma unroll
  for (int off = 1; off < SUBS; off <<= 1) {
    a0 += __shfl_xor(a0, off);
    a1 += __shfl_xor(a1, off);
    a2 += __shfl_xor(a2, off);
    a3 += __shfl_xor(a3, off);
  }

  if (sub == 0) {
    const float nrm = 1.0f / 63.5f;  // sum(apod) == 63.5 analytically
    out[0 * NPIX + p] = a0 * nrm;
    out[1 * NPIX + p] = a1 * nrm;
    out[2 * NPIX + p] = a2 * nrm;
    out[3 * NPIX + p] = a3 * nrm;
  }
}

// Fallback (no workspace): direct fp32 gather from original layout.
__global__ __launch_bounds__(256) void das_fallback_kernel(
    const float* __restrict__ lut, const float* __restrict__ S,
    float* __restrict__ out) {
  const int lane = threadIdx.x & 63;
  const int p = blockIdx.x * 4 + (threadIdx.x >> 6);

  const float4 lv =
      reinterpret_cast<const float4*>(lut + (size_t)p * 2 * N_DET)[lane];

  float acc0 = 0.f, acc1 = 0.f, acc2 = 0.f, acc3 = 0.f;
  float wsum = 0.f;

#pragma unroll
  for (int j = 0; j < 2; ++j) {
    const int d = 2 * lane + j;
    const float tof = j ? lv.z : lv.x;
    const float a   = j ? lv.w : lv.y;
    const float kf = floorf(tof);
    const bool valid = (kf >= 0.0f) && (kf < (float)(N_T - 1));
    const float kcl = fminf(fmaxf(kf, 0.0f), (float)(N_T - 2));
    const int k0 = (int)kcl;
    const float apd =
        0.5f - 0.5f * cosf(6.28318530717958647692f *
                           (1.0f / (float)(N_DET - 1)) * (float)d);
    wsum += apd;
    const float w = valid ? apd : 0.0f;
    const float om = 1.0f - a;
    const float* row = S + (size_t)d * N_T + k0;
    acc0 += w * (om * row[0 * N_DET * N_T] + a * row[0 * N_DET * N_T + 1]);
    acc1 += w * (om * row[1 * N_DET * N_T] + a * row[1 * N_DET * N_T + 1]);
    acc2 += w * (om * row[2 * N_DET * N_T] + a * row[2 * N_DET * N_T + 1]);
    acc3 += w * (om * row[3 * N_DET * N_T] + a * row[3 * N_DET * N_T + 1]);
  }

#pragma unroll
  for (int off = 32; off > 0; off >>= 1) {
    acc0 += __shfl_xor(acc0, off);
    acc1 += __shfl_xor(acc1, off);
    acc2 += __shfl_xor(acc2, off);
    acc3 += __shfl_xor(acc3, off);
    wsum += __shfl_xor(wsum, off);
  }

  if (lane == 0) {
    const float inv = 1.0f / fmaxf(wsum, 1.17549435e-38f);
    out[0 * NPIX + p] = acc0 * inv;
    out[1 * NPIX + p] = acc1 * inv;
    out[2 * NPIX + p] = acc2 * inv;
    out[3 * NPIX + p] = acc3 * inv;
  }
}

extern "C" void kernel_launch(void* const* d_in, const int* in_sizes, int n_in,
                              void* d_out, int out_size, void* d_ws, size_t ws_size,
                              hipStream_t stream) {
  const float* sino = (const float*)d_in[0];  // (B,1,N_DET,N_T) fp32
  const float* lut  = (const float*)d_in[1];  // (NY,NX,N_DET,2) fp32
  float* out = (float*)d_out;                 // (B,1,NY,NX) fp32

  const size_t need = (size_t)N_DET * N_T * 8;  // 2 MB packed ws
  if (ws_size >= need) {
    float2* ws = (float2*)d_ws;
    sino_pack_kernel<<<(N_DET * N_T) / 256, 256, 0, stream>>>(sino, ws);
    das_gather_kernel<<<(NPIX * SUBS) / 256, 256, 0, stream>>>(
        lut, (const char*)ws, out);
  } else {
    das_fallback_kernel<<<NPIX / 4, 256, 0, stream>>>(lut, sino, out);
  }
}

// Round 5
// 123.737 us; speedup vs baseline: 1.8568x; 1.0185x over previous
//
#include <hip/hip_runtime.h>
#include <hip/hip_fp16.h>

#define N_DET 128
#define N_T   2048
#define NPIX  65536   // 256*256
#define NBATCH 4
#define G 4                   // det rows per block (4 x 16 KB = 64 KB LDS)
#define NGRP (N_DET / G)      // 32 det-group blocks per pixel
#define TPX 2048              // pixels per tile
#define NTILE (NPIX / TPX)    // 32
#define PXT 4                 // pixels per thread (512 threads x 4 = 2048)

typedef float f4_t __attribute__((ext_vector_type(4)));

// Kernel 1: transpose+pack sino (B, N_DET, N_T) fp32 -> ws (N_DET, N_T) of
// 8-byte records { s_t[b0..b3] } as 4 fp16. ws = 2 MB (L2-resident per XCD).
// Also zeroes out[] (N_DET*N_T == NBATCH*NPIX == 262144 floats) for the
// atomic accumulation in kernel 2.
__global__ __launch_bounds__(256) void sino_pack_kernel(
    const float* __restrict__ sino, float2* __restrict__ ws,
    float* __restrict__ out) {
  const int idx = blockIdx.x * blockDim.x + threadIdx.x;  // idx = d*N_T + t
  const __half2 lo = __floats2half2_rn(
      __builtin_nontemporal_load(sino + 0 * N_DET * N_T + idx),
      __builtin_nontemporal_load(sino + 1 * N_DET * N_T + idx));
  const __half2 hi = __floats2half2_rn(
      __builtin_nontemporal_load(sino + 2 * N_DET * N_T + idx),
      __builtin_nontemporal_load(sino + 3 * N_DET * N_T + idx));
  union { struct { __half2 a, b; } h; float2 f; } u;
  u.h.a = lo;
  u.h.b = hi;
  ws[idx] = u.f;
  out[idx] = 0.0f;  // exact cover: 128*2048 == 4*65536
}

// Kernel 2: G=4 LDS-gather.
//  - Gathers go through the LDS pipe (r4 lesson: TA-path random 16 B gathers
//    cost ~64 lines/wave + 4x L2 amplification; LDS serves them at
//    32 banks/cycle).
//  - 64 KB LDS -> 2 resident blocks/CU: one block's lut/stage loads overlap
//    the other's compute (r0 lesson: 1 block/CU has ~25% memory duty cycle ->
//    lut stream stuck at 1.4 TB/s).
//  - launch_bounds(512,4): VGPR cap 128, est ~90 (r1/r4 lesson: tighter
//    bounds strangle VGPRs and serialize the load chains).
//  - XCD swizzle: all 32 det-group blocks of a tile land on the SAME XCD,
//    adjacent in dispatch, so same-line atomicAdds merge in that XCD's L2
//    (r2 lesson: time-scattered det-split atomics cost +45 MB HBM RMW).
//    id = (T>>3)*256 + g*8 + (T&7)  (bijective on [0,1024))
__global__ __launch_bounds__(512, 4) void das_lds_kernel(
    const float* __restrict__ lut, const float2* __restrict__ ws,
    float* __restrict__ out) {
  __shared__ __align__(16) float2 sbuf[G][N_T];  // 64 KB

  const int id = blockIdx.x;
  const int T = ((id >> 8) << 3) | (id & 7);  // tile 0..31 (same XCD for all g)
  const int g = (id >> 3) & 31;               // det-group 0..31
  const int tid = threadIdx.x;

  // 1) lut loads first: 4 px x 32 B (2 b128 each) = 8 b128 in flight.
  //    Per px the 32 B covers this group's 4 dets: (tof,alpha) x 4.
  f4_t l[PXT][2];
  const char* lb = reinterpret_cast<const char*>(lut);
#pragma unroll
  for (int i = 0; i < PXT; ++i) {
    const size_t P = (size_t)T * TPX + i * 512 + tid;
    const f4_t* lp = reinterpret_cast<const f4_t*>(lb + P * (N_DET * 8) +
                                                   (size_t)g * (G * 8));
    l[i][0] = lp[0];
    l[i][1] = lp[1];
  }

  // 2) Stage 4 det rows (64 KB) from L2-resident ws via async global_load_lds.
  //    Linear mapping: wave-uniform base + lane*16 (HW requirement).
  {
    const char* src = reinterpret_cast<const char*>(ws) + (size_t)g * 65536;
    char* dstb = reinterpret_cast<char*>(&sbuf[0][0]);
#pragma unroll
    for (int r = 0; r < 8; ++r) {
      __builtin_amdgcn_global_load_lds(
          (const __attribute__((address_space(1))) void*)(src + r * 8192 +
                                                          tid * 16),
          (__attribute__((address_space(3))) void*)(dstb + r * 8192 + tid * 16),
          16, 0, 0);
    }
  }

  // Apodization for this group's 4 dets (wave-uniform).
  float apd[G];
#pragma unroll
  for (int dd = 0; dd < G; ++dd)
    apd[dd] = 0.5f - 0.5f * cosf(6.28318530717958647692f *
                                 ((float)(g * G + dd) / 127.0f));

  __syncthreads();  // drains stage (and lut loads, needed right after anyway)

  float4 acc[PXT];
#pragma unroll
  for (int i = 0; i < PXT; ++i) acc[i] = make_float4(0.f, 0.f, 0.f, 0.f);

#pragma unroll
  for (int i = 0; i < PXT; ++i) {
#pragma unroll
    for (int dd = 0; dd < G; ++dd) {
      const float tof = (dd & 1) ? l[i][dd >> 1].z : l[i][dd >> 1].x;
      const float al  = (dd & 1) ? l[i][dd >> 1].w : l[i][dd >> 1].y;
      const float kf = floorf(tof);
      const bool valid = (kf >= 0.0f) && (kf < (float)(N_T - 1));
      const int k0 = (int)fminf(fmaxf(kf, 0.0f), (float)(N_T - 2));
      const float w = valid ? apd[dd] : 0.0f;

      const float2 r0 = sbuf[dd][k0];      // ds_read_b64: tap t
      const float2 r1 = sbuf[dd][k0 + 1];  // ds_read_b64: tap t+1
      const __half2* h0 = reinterpret_cast<const __half2*>(&r0);
      const __half2* h1 = reinterpret_cast<const __half2*>(&r1);
      const float2 s0a = __half22float2(h0[0]);  // t:   b0,b1
      const float2 s0b = __half22float2(h0[1]);  // t:   b2,b3
      const float2 s1a = __half22float2(h1[0]);  // t+1: b0,b1
      const float2 s1b = __half22float2(h1[1]);  // t+1: b2,b3

      acc[i].x += w * (s0a.x + al * (s1a.x - s0a.x));
      acc[i].y += w * (s0a.y + al * (s1a.y - s0a.y));
      acc[i].z += w * (s0b.x + al * (s1b.x - s0b.x));
      acc[i].w += w * (s0b.y + al * (s1b.y - s0b.y));
    }
  }

  const float nrm = 1.0f / 63.5f;  // sum(apod) == 63.5 analytically
#pragma unroll
  for (int i = 0; i < PXT; ++i) {
    const int P = T * TPX + i * 512 + tid;
    atomicAdd(out + 0 * NPIX + P, acc[i].x * nrm);
    atomicAdd(out + 1 * NPIX + P, acc[i].y * nrm);
    atomicAdd(out + 2 * NPIX + P, acc[i].z * nrm);
    atomicAdd(out + 3 * NPIX + P, acc[i].w * nrm);
  }
}

// Fallback (no workspace): direct fp32 gather from original layout.
__global__ __launch_bounds__(256) void das_fallback_kernel(
    const float* __restrict__ lut, const float* __restrict__ S,
    float* __restrict__ out) {
  const int lane = threadIdx.x & 63;
  const int p = blockIdx.x * 4 + (threadIdx.x >> 6);

  const float4 lv =
      reinterpret_cast<const float4*>(lut + (size_t)p * 2 * N_DET)[lane];

  float acc0 = 0.f, acc1 = 0.f, acc2 = 0.f, acc3 = 0.f;
  float wsum = 0.f;

#pragma unroll
  for (int j = 0; j < 2; ++j) {
    const int d = 2 * lane + j;
    const float tof = j ? lv.z : lv.x;
    const float a   = j ? lv.w : lv.y;
    const float kf = floorf(tof);
    const bool valid = (kf >= 0.0f) && (kf < (float)(N_T - 1));
    const float kcl = fminf(fmaxf(kf, 0.0f), (float)(N_T - 2));
    const int k0 = (int)kcl;
    const float apd =
        0.5f - 0.5f * cosf(6.28318530717958647692f *
                           (1.0f / (float)(N_DET - 1)) * (float)d);
    wsum += apd;
    const float w = valid ? apd : 0.0f;
    const float om = 1.0f - a;
    const float* row = S + (size_t)d * N_T + k0;
    acc0 += w * (om * row[0 * N_DET * N_T] + a * row[0 * N_DET * N_T + 1]);
    acc1 += w * (om * row[1 * N_DET * N_T] + a * row[1 * N_DET * N_T + 1]);
    acc2 += w * (om * row[2 * N_DET * N_T] + a * row[2 * N_DET * N_T + 1]);
    acc3 += w * (om * row[3 * N_DET * N_T] + a * row[3 * N_DET * N_T + 1]);
  }

#pragma unroll
  for (int off = 32; off > 0; off >>= 1) {
    acc0 += __shfl_xor(acc0, off);
    acc1 += __shfl_xor(acc1, off);
    acc2 += __shfl_xor(acc2, off);
    acc3 += __shfl_xor(acc3, off);
    wsum += __shfl_xor(wsum, off);
  }

  if (lane == 0) {
    const float inv = 1.0f / fmaxf(wsum, 1.17549435e-38f);
    out[0 * NPIX + p] = acc0 * inv;
    out[1 * NPIX + p] = acc1 * inv;
    out[2 * NPIX + p] = acc2 * inv;
    out[3 * NPIX + p] = acc3 * inv;
  }
}

extern "C" void kernel_launch(void* const* d_in, const int* in_sizes, int n_in,
                              void* d_out, int out_size, void* d_ws, size_t ws_size,
                              hipStream_t stream) {
  const float* sino = (const float*)d_in[0];  // (B,1,N_DET,N_T) fp32
  const float* lut  = (const float*)d_in[1];  // (NY,NX,N_DET,2) fp32
  float* out = (float*)d_out;                 // (B,1,NY,NX) fp32

  const size_t need = (size_t)N_DET * N_T * 8;  // 2 MB packed ws
  if (ws_size >= need) {
    float2* ws = (float2*)d_ws;
    sino_pack_kernel<<<(N_DET * N_T) / 256, 256, 0, stream>>>(sino, ws, out);
    das_lds_kernel<<<NTILE * NGRP, 512, 0, stream>>>(lut, ws, out);
  } else {
    das_fallback_kernel<<<NPIX / 4, 256, 0, stream>>>(lut, sino, out);
  }
}